// Round 15
// baseline (29.716 us; speedup 1.0000x reference)
//
#include <hip/hip_runtime.h>
#include <hip/hip_fp16.h>
#include <math.h>

#define THREADS 128   // 2 waves/block; [24][128] u32 LDS = 12.3KB (R13 shape, best known: 26.26us)

__device__ __forceinline__ float prcp(float x) { return __builtin_amdgcn_rcpf(x); }

__device__ __forceinline__ unsigned packh2(float x, float y) {
    __half2 h = __floats2half2_rn(x, y);
    return *reinterpret_cast<unsigned*>(&h);
}
__device__ __forceinline__ void unpackh2(unsigned u, float& x, float& y) {
    __half2 h = *reinterpret_cast<__half2*>(&u);
    x = __low2float(h); y = __high2float(h);
}

__global__ void __launch_bounds__(THREADS) iou3d_kernel(
    const float* __restrict__ pred, const float* __restrict__ tgt,
    const float* __restrict__ wgt, float* __restrict__ partial, int N) {
    __shared__ unsigned ldsbuf[24 * THREADS];   // slot-major: bank = tid%32, conflict-free
    int tid = threadIdx.x;
#define LDSV(S) ldsbuf[((S) << 7) + tid]
    int n = blockIdx.x * THREADS + tid;
    float loss = 0.0f;
    if (n < N) {
        float p[7], t[7];
#pragma unroll
        for (int k = 0; k < 7; k++) {
            p[k] = pred[(size_t)n * 7 + k];
            float tv = tgt[(size_t)n * 7 + k];
            t[k] = (tv != tv) ? p[k] : tv;
        }
        float w = wgt[n];
        float zmax1 = p[2] + p[5] * 0.5f, zmin1 = p[2] - p[5] * 0.5f;
        float zmax2 = t[2] + t[5] * 0.5f, zmin2 = t[2] - t[5] * 0.5f;
        float zov = fmaxf(fminf(zmax1, zmax2) - fmaxf(zmin1, zmin2), 0.0f);
        float volsum = p[3] * p[4] * p[5] + t[3] * t[4] * t[5];

        float hw1 = 0.5f * p[3], hh1 = 0.5f * p[4];
        float hw2 = 0.5f * t[3], hh2 = 0.5f * t[4];
        float s1, c1v, s2, c2v;
        __sincosf(p[6], &s1, &c1v);
        __sincosf(t[6], &s2, &c2v);
        float c12 = c1v * c2v + s1 * s2;
        float s12 = s1 * c2v - c1v * s2;
        float ddx = p[0] - t[0], ddy = p[1] - t[1];
        float T12x =  c2v * ddx + s2 * ddy;
        float T12y = -s2 * ddx + c2v * ddy;
        float T21x = -(c1v * ddx + s1 * ddy);
        float T21y =  s1 * ddx - c1v * ddy;
        float ux = c12 * hw1, uy = s12 * hw1;
        float wx = -s12 * hh1, wy = c12 * hh1;
        float fx[4], fy[4];
        fx[0] = T12x + ux + wx; fy[0] = T12y + uy + wy;
        fx[1] = T12x - ux + wx; fy[1] = T12y - uy + wy;
        fx[2] = T12x - ux - wx; fy[2] = T12y - uy - wy;
        fx[3] = T12x + ux - wx; fy[3] = T12y + uy - wy;

        unsigned vm = 0;
        float bx2 = hw2 * (1.0f + 2e-6f), by2 = hh2 * (1.0f + 2e-6f);
#pragma unroll
        for (int k = 0; k < 4; k++) {
            bool c = (fabsf(fx[k]) < bx2) && (fabsf(fy[k]) < by2);
            vm |= ((unsigned)c) << k;
        }
        float u2x = c12 * hw2, u2y = -s12 * hw2;
        float v2x = s12 * hh2, v2y = c12 * hh2;
        float bx1 = hw1 * (1.0f + 2e-6f), by1 = hh1 * (1.0f + 2e-6f);
        {
            float qx, qy;
            qx = T21x + u2x + v2x; qy = T21y + u2y + v2y;
            vm |= ((unsigned)((fabsf(qx) < bx1) && (fabsf(qy) < by1))) << 4;
            qx = T21x - u2x + v2x; qy = T21y - u2y + v2y;
            vm |= ((unsigned)((fabsf(qx) < bx1) && (fabsf(qy) < by1))) << 5;
            qx = T21x - u2x - v2x; qy = T21y - u2y - v2y;
            vm |= ((unsigned)((fabsf(qx) < bx1) && (fabsf(qy) < by1))) << 6;
            qx = T21x + u2x - v2x; qy = T21y + u2y - v2y;
            vm |= ((unsigned)((fabsf(qx) < bx1) && (fabsf(qy) < by1))) << 7;
        }
        // masked centroid sums: split into 2 accumulator pairs to break serial chains
        float sxa = 0.0f, sya = 0.0f, sxb = 0.0f, syb = 0.0f;
#pragma unroll
        for (int k = 0; k < 4; k++) {
            LDSV(k) = packh2(fx[k], fy[k]);
            bool v = (vm >> k) & 1u;
            if (k & 1) { sxb += v ? fx[k] : 0.0f; syb += v ? fy[k] : 0.0f; }
            else       { sxa += v ? fx[k] : 0.0f; sya += v ? fy[k] : 0.0f; }
        }
        LDSV(4) = packh2(hw2, hh2);   LDSV(5) = packh2(-hw2, hh2);
        LDSV(6) = packh2(-hw2, -hh2); LDSV(7) = packh2(hw2, -hh2);
        {
            bool v4 = (vm >> 4) & 1u, v5 = (vm >> 5) & 1u, v6 = (vm >> 6) & 1u, v7 = (vm >> 7) & 1u;
            sxa += (v4 ? hw2 : 0.0f) + (v6 ? -hw2 : 0.0f);
            sxb += (v5 ? -hw2 : 0.0f) + (v7 ? hw2 : 0.0f);
            sya += (v4 ? hh2 : 0.0f) + (v6 ? -hh2 : 0.0f);
            syb += (v5 ? hh2 : 0.0f) + (v7 ? -hh2 : 0.0f);
        }

        // 16 intersections in frame2; exact reference-accepted set.
        // u-test collapsed to coordinate range test (R8/R9-verified identical):
        //   e2=0: u in (0,1) <=> px in ( hw2, 3hw2) ; e2=1: py in ( hh2, 3hh2)
        //   e2=2: u in (0,1) <=> px in (-3hw2,-hw2) ; e2=3: py in (-3hh2,-hh2)
        float tux = ux + ux, tuy = uy + uy, twx = wx + wx, twy = wy + wy;
        float rtux = prcp(tux), rtuy = prcp(tuy), rtwx = prcp(twx), rtwy = prcp(twy);
        float dxe[4] = {-tux, -twx, tux, twx};
        float dye[4] = {-tuy, -twy, tuy, twy};
        float rdxe[4] = {-rtux, -rtwx, rtux, rtwx};
        float rdye[4] = {-rtuy, -rtwy, rtuy, rtwy};
        float w3 = 3.0f * hw2, h3 = 3.0f * hh2;
        float pvar[16];
#pragma unroll
        for (int e1 = 0; e1 < 4; e1++) {
            float x1 = fx[e1], y1 = fy[e1];
            {   // e2 = 0: Y = +hh2
                float tt = (hh2 - y1) * rdye[e1];
                float px = fmaf(tt, dxe[e1], x1);
                bool mk = (tt > 0.0f) && (tt < 1.0f) && (px > hw2) && (px < w3);
                pvar[e1 * 4 + 0] = px;
                float pxm = mk ? px : 0.0f, pym = mk ? hh2 : 0.0f;
                LDSV(8 + e1 * 4 + 0) = packh2(pxm, pym);
                sxa += pxm; sya += pym;
                vm |= ((unsigned)mk) << (8 + e1 * 4 + 0);
            }
            {   // e2 = 1: X = -hw2
                float tt = (-hw2 - x1) * rdxe[e1];
                float py = fmaf(tt, dye[e1], y1);
                bool mk = (tt > 0.0f) && (tt < 1.0f) && (py > hh2) && (py < h3);
                pvar[e1 * 4 + 1] = py;
                float pxm = mk ? -hw2 : 0.0f, pym = mk ? py : 0.0f;
                LDSV(8 + e1 * 4 + 1) = packh2(pxm, pym);
                sxb += pxm; syb += pym;
                vm |= ((unsigned)mk) << (8 + e1 * 4 + 1);
            }
            {   // e2 = 2: Y = -hh2
                float tt = (-hh2 - y1) * rdye[e1];
                float px = fmaf(tt, dxe[e1], x1);
                bool mk = (tt > 0.0f) && (tt < 1.0f) && (px < -hw2) && (px > -w3);
                pvar[e1 * 4 + 2] = px;
                float pxm = mk ? px : 0.0f, pym = mk ? -hh2 : 0.0f;
                LDSV(8 + e1 * 4 + 2) = packh2(pxm, pym);
                sxa += pxm; sya += pym;
                vm |= ((unsigned)mk) << (8 + e1 * 4 + 2);
            }
            {   // e2 = 3: X = +hw2
                float tt = (hw2 - x1) * rdxe[e1];
                float py = fmaf(tt, dye[e1], y1);
                bool mk = (tt > 0.0f) && (tt < 1.0f) && (py < -hh2) && (py > -h3);
                pvar[e1 * 4 + 3] = py;
                float pxm = mk ? hw2 : 0.0f, pym = mk ? py : 0.0f;
                LDSV(8 + e1 * 4 + 3) = packh2(pxm, pym);
                sxb += pxm; syb += pym;
                vm |= ((unsigned)mk) << (8 + e1 * 4 + 3);
            }
        }
        float sx = sxa + sxb, sy = sya + syb;

        int nv = __popc(vm);
        float r0 = prcp(fmaxf((float)nv, 1.0f));
        float mx = sx * r0, my = sy * r0;

        unsigned ka[24];
#define MKKEY(K, XR, YR) do { \
        float xr_ = (XR), yr_ = (YR); \
        float d_ = fabsf(xr_) + fabsf(yr_); \
        float q_ = 1.0f - xr_ * prcp(d_); \
        float pa_ = copysignf(q_, yr_) + 4.0f; \
        unsigned key_ = (__float_as_uint(pa_) & 0xFFFFFFE0u) | (unsigned)(K); \
        ka[K] = ((vm >> (K)) & 1u) ? key_ : (0x7F000000u | (unsigned)(K)); \
    } while (0)
        float hpx = hw2 - mx, hmx = -hw2 - mx, hpy = hh2 - my, hmy = -hh2 - my;
#pragma unroll
        for (int k = 0; k < 4; k++) MKKEY(k, fx[k] - mx, fy[k] - my);
        MKKEY(4, hpx, hpy); MKKEY(5, hmx, hpy); MKKEY(6, hmx, hmy); MKKEY(7, hpx, hmy);
#pragma unroll
        for (int e1 = 0; e1 < 4; e1++) {
            MKKEY(8 + e1 * 4 + 0, pvar[e1 * 4 + 0] - mx, hpy);
            MKKEY(8 + e1 * 4 + 1, hmx, pvar[e1 * 4 + 1] - my);
            MKKEY(8 + e1 * 4 + 2, pvar[e1 * 4 + 2] - mx, hmy);
            MKKEY(8 + e1 * 4 + 3, hpx, pvar[e1 * 4 + 3] - my);
        }
#undef MKKEY

        // Batcher odd-even mergesort, n=24 (132 CEs), u32 min/max
#define CE(A, B) { unsigned lo_ = ka[A] < ka[B] ? ka[A] : ka[B]; \
                   unsigned hi_ = ka[A] < ka[B] ? ka[B] : ka[A]; \
                   ka[A] = lo_; ka[B] = hi_; }
        CE(0,1); CE(2,3); CE(4,5); CE(6,7); CE(8,9); CE(10,11); CE(12,13); CE(14,15); CE(16,17); CE(18,19); CE(20,21); CE(22,23);
        CE(0,2); CE(1,3); CE(4,6); CE(5,7); CE(8,10); CE(9,11); CE(12,14); CE(13,15); CE(16,18); CE(17,19); CE(20,22); CE(21,23);
        CE(1,2); CE(5,6); CE(9,10); CE(13,14); CE(17,18); CE(21,22);
        CE(0,4); CE(1,5); CE(2,6); CE(3,7); CE(8,12); CE(9,13); CE(10,14); CE(11,15); CE(16,20); CE(17,21); CE(18,22); CE(19,23);
        CE(2,4); CE(3,5); CE(10,12); CE(11,13); CE(18,20); CE(19,21);
        CE(1,2); CE(3,4); CE(5,6); CE(9,10); CE(11,12); CE(13,14); CE(17,18); CE(19,20); CE(21,22);
        CE(0,8); CE(1,9); CE(2,10); CE(3,11); CE(4,12); CE(5,13); CE(6,14); CE(7,15);
        CE(4,8); CE(5,9); CE(6,10); CE(7,11);
        CE(2,4); CE(3,5); CE(6,8); CE(7,9); CE(10,12); CE(11,13); CE(18,20); CE(19,21);
        CE(1,2); CE(3,4); CE(5,6); CE(7,8); CE(9,10); CE(11,12); CE(13,14); CE(17,18); CE(19,20); CE(21,22);
        CE(0,16); CE(1,17); CE(2,18); CE(3,19); CE(4,20); CE(5,21); CE(6,22); CE(7,23);
        CE(8,16); CE(9,17); CE(10,18); CE(11,19); CE(12,20); CE(13,21); CE(14,22); CE(15,23);
        CE(4,8); CE(5,9); CE(6,10); CE(7,11); CE(12,16); CE(13,17); CE(14,18); CE(15,19);
        CE(2,4); CE(3,5); CE(6,8); CE(7,9); CE(10,12); CE(11,13); CE(14,16); CE(15,17); CE(18,20); CE(19,21);
        CE(1,2); CE(3,4); CE(5,6); CE(7,8); CE(9,10); CE(11,12); CE(13,14); CE(15,16); CE(17,18); CE(19,20); CE(21,22);
#undef CE

        // gather sorted vertices; ref-exact cyclic shoelace with 4 rotating accumulators
        unsigned gu[24];
#pragma unroll
        for (int i = 0; i < 24; i++) gu[i] = ldsbuf[((ka[i] & 31u) << 7) + tid];
        float g0x, g0y;
        unpackh2(gu[0], g0x, g0y);
        float prevx = g0x, prevy = g0y;
        float ar0 = 0.0f, ar1 = 0.0f, ar2 = 0.0f, ar3 = 0.0f;
#pragma unroll
        for (int i = 1; i < 24; i++) {
            float xx, yy;
            unpackh2(gu[i], xx, yy);
            bool c = i < nv;
            float cxv = c ? xx : g0x;
            float cyv = c ? yy : g0y;
            float cr = prevx * cyv - cxv * prevy;
            if ((i & 3) == 0) ar0 += cr;
            else if ((i & 3) == 1) ar1 += cr;
            else if ((i & 3) == 2) ar2 += cr;
            else ar3 += cr;
            prevx = cxv; prevy = cyv;
        }
        ar0 += prevx * g0y - g0x * prevy;
        float area2 = (ar0 + ar1) + (ar2 + ar3);
        float inter2d = 0.5f * fabsf(area2);

        float inter3d = inter2d * zov;
        float uni = volsum - inter3d;
        float iou = inter3d / uni;
        loss = (1.0f - iou) * w;
    }
#undef LDSV

    // block reduction: wave shuffle + 2-wave LDS combine
#pragma unroll
    for (int off = 32; off > 0; off >>= 1) loss += __shfl_down(loss, off, 64);
    __shared__ float sm[THREADS / 64];
    int lane = threadIdx.x & 63, wv = threadIdx.x >> 6;
    if (lane == 0) sm[wv] = loss;
    __syncthreads();
    if (threadIdx.x == 0) {
        float s = 0.0f;
#pragma unroll
        for (int k = 0; k < THREADS / 64; k++) s += sm[k];
        partial[blockIdx.x] = s;
    }
}

__global__ void __launch_bounds__(1024) reduce_kernel(const float* __restrict__ partial,
                                                      int nb, float* __restrict__ out, int N) {
    float s = 0.0f;
    for (int i = threadIdx.x; i < nb; i += 1024) s += partial[i];
#pragma unroll
    for (int off = 32; off > 0; off >>= 1) s += __shfl_down(s, off, 64);
    __shared__ float sm[16];
    int lane = threadIdx.x & 63, wv = threadIdx.x >> 6;
    if (lane == 0) sm[wv] = s;
    __syncthreads();
    if (threadIdx.x == 0) {
        float tot = 0.0f;
#pragma unroll
        for (int k = 0; k < 16; k++) tot += sm[k];
        out[0] = tot / (float)N;
    }
}

extern "C" void kernel_launch(void* const* d_in, const int* in_sizes, int n_in,
                              void* d_out, int out_size, void* d_ws, size_t ws_size,
                              hipStream_t stream) {
    const float* pred = (const float*)d_in[0];
    const float* tgt  = (const float*)d_in[1];
    const float* wgt  = (const float*)d_in[2];
    int N = in_sizes[2];
    int nb = (N + THREADS - 1) / THREADS;
    float* partial = (float*)d_ws;
    iou3d_kernel<<<nb, THREADS, 0, stream>>>(pred, tgt, wgt, partial, N);
    reduce_kernel<<<1, 1024, 0, stream>>>(partial, nb, (float*)d_out, N);
}

// Round 16
// 26.043 us; speedup vs baseline: 1.1410x; 1.1410x over previous
//
#include <hip/hip_runtime.h>
#include <hip/hip_fp16.h>
#include <math.h>

#define THREADS 128   // 2 waves/block; [24][128] u32 LDS = 12.3KB (R13 shape, best known)

__device__ __forceinline__ float prcp(float x) { return __builtin_amdgcn_rcpf(x); }

__device__ __forceinline__ unsigned packh2(float x, float y) {
    __half2 h = __floats2half2_rn(x, y);
    return *reinterpret_cast<unsigned*>(&h);
}
__device__ __forceinline__ void unpackh2(unsigned u, float& x, float& y) {
    __half2 h = *reinterpret_cast<__half2*>(&u);
    x = __low2float(h); y = __high2float(h);
}

__global__ void __launch_bounds__(THREADS) iou3d_kernel(
    const float* __restrict__ pred, const float* __restrict__ tgt,
    const float* __restrict__ wgt, float* __restrict__ partial, int N) {
    __shared__ unsigned ldsbuf[24 * THREADS];   // slot-major: bank = tid%32, conflict-free
    int tid = threadIdx.x;
#define LDSV(S) ldsbuf[((S) << 7) + tid]
    int n = blockIdx.x * THREADS + tid;
    float loss = 0.0f;
    if (n < N) {
        float p[7], t[7];
#pragma unroll
        for (int k = 0; k < 7; k++) {
            p[k] = pred[(size_t)n * 7 + k];
            float tv = tgt[(size_t)n * 7 + k];
            t[k] = (tv != tv) ? p[k] : tv;
        }
        float w = wgt[n];
        float zmax1 = p[2] + p[5] * 0.5f, zmin1 = p[2] - p[5] * 0.5f;
        float zmax2 = t[2] + t[5] * 0.5f, zmin2 = t[2] - t[5] * 0.5f;
        float zov = fmaxf(fminf(zmax1, zmax2) - fmaxf(zmin1, zmin2), 0.0f);
        float volsum = p[3] * p[4] * p[5] + t[3] * t[4] * t[5];

        float hw1 = 0.5f * p[3], hh1 = 0.5f * p[4];
        float hw2 = 0.5f * t[3], hh2 = 0.5f * t[4];
        float s1, c1v, s2, c2v;
        __sincosf(p[6], &s1, &c1v);
        __sincosf(t[6], &s2, &c2v);
        float c12 = c1v * c2v + s1 * s2;
        float s12 = s1 * c2v - c1v * s2;
        float ddx = p[0] - t[0], ddy = p[1] - t[1];
        float T12x =  c2v * ddx + s2 * ddy;
        float T12y = -s2 * ddx + c2v * ddy;
        float T21x = -(c1v * ddx + s1 * ddy);
        float T21y =  s1 * ddx - c1v * ddy;
        float ux = c12 * hw1, uy = s12 * hw1;
        float wx = -s12 * hh1, wy = c12 * hh1;
        float fx[4], fy[4];
        fx[0] = T12x + ux + wx; fy[0] = T12y + uy + wy;
        fx[1] = T12x - ux + wx; fy[1] = T12y - uy + wy;
        fx[2] = T12x - ux - wx; fy[2] = T12y - uy - wy;
        fx[3] = T12x + ux - wx; fy[3] = T12y + uy - wy;

        unsigned vm = 0;
        float bx2 = hw2 * (1.0f + 2e-6f), by2 = hh2 * (1.0f + 2e-6f);
#pragma unroll
        for (int k = 0; k < 4; k++) {
            bool c = (fabsf(fx[k]) < bx2) && (fabsf(fy[k]) < by2);
            vm |= ((unsigned)c) << k;
        }
        float u2x = c12 * hw2, u2y = -s12 * hw2;
        float v2x = s12 * hh2, v2y = c12 * hh2;
        float bx1 = hw1 * (1.0f + 2e-6f), by1 = hh1 * (1.0f + 2e-6f);
        {
            float qx, qy;
            qx = T21x + u2x + v2x; qy = T21y + u2y + v2y;
            vm |= ((unsigned)((fabsf(qx) < bx1) && (fabsf(qy) < by1))) << 4;
            qx = T21x - u2x + v2x; qy = T21y - u2y + v2y;
            vm |= ((unsigned)((fabsf(qx) < bx1) && (fabsf(qy) < by1))) << 5;
            qx = T21x - u2x - v2x; qy = T21y - u2y - v2y;
            vm |= ((unsigned)((fabsf(qx) < bx1) && (fabsf(qy) < by1))) << 6;
            qx = T21x + u2x - v2x; qy = T21y + u2y - v2y;
            vm |= ((unsigned)((fabsf(qx) < bx1) && (fabsf(qy) < by1))) << 7;
        }
        // masked centroid sums: split into 2 accumulator pairs to break serial chains
        float sxa = 0.0f, sya = 0.0f, sxb = 0.0f, syb = 0.0f;
#pragma unroll
        for (int k = 0; k < 4; k++) {
            LDSV(k) = packh2(fx[k], fy[k]);
            bool v = (vm >> k) & 1u;
            if (k & 1) { sxb += v ? fx[k] : 0.0f; syb += v ? fy[k] : 0.0f; }
            else       { sxa += v ? fx[k] : 0.0f; sya += v ? fy[k] : 0.0f; }
        }
        LDSV(4) = packh2(hw2, hh2);   LDSV(5) = packh2(-hw2, hh2);
        LDSV(6) = packh2(-hw2, -hh2); LDSV(7) = packh2(hw2, -hh2);
        {
            bool v4 = (vm >> 4) & 1u, v5 = (vm >> 5) & 1u, v6 = (vm >> 6) & 1u, v7 = (vm >> 7) & 1u;
            sxa += (v4 ? hw2 : 0.0f) + (v6 ? -hw2 : 0.0f);
            sxb += (v5 ? -hw2 : 0.0f) + (v7 ? hw2 : 0.0f);
            sya += (v4 ? hh2 : 0.0f) + (v6 ? -hh2 : 0.0f);
            syb += (v5 ? hh2 : 0.0f) + (v7 ? -hh2 : 0.0f);
        }

        // 16 intersections in frame2; exact reference semantics (incl. u-sign quirk)
        float tux = ux + ux, tuy = uy + uy, twx = wx + wx, twy = wy + wy;
        float rtux = prcp(tux), rtuy = prcp(tuy), rtwx = prcp(twx), rtwy = prcp(twy);
        float dxe[4] = {-tux, -twx, tux, twx};
        float dye[4] = {-tuy, -twy, tuy, twy};
        float rdxe[4] = {-rtux, -rtwx, rtux, rtwx};
        float rdye[4] = {-rtuy, -rtwy, rtuy, rtwy};
        float r2w = prcp(hw2 + hw2), r2h = prcp(hh2 + hh2);
        float pvar[16];
#pragma unroll
        for (int e1 = 0; e1 < 4; e1++) {
            float x1 = fx[e1], y1 = fy[e1];
            {   // e2 = 0: Y = +hh2
                float tt = (hh2 - y1) * rdye[e1];
                float px = fmaf(tt, dxe[e1], x1);
                float uu = (hw2 - px) * (-r2w);
                bool mk = (tt > 0.0f) && (tt < 1.0f) && (uu > 0.0f) && (uu < 1.0f);
                pvar[e1 * 4 + 0] = px;
                float pxm = mk ? px : 0.0f, pym = mk ? hh2 : 0.0f;
                LDSV(8 + e1 * 4 + 0) = packh2(pxm, pym);
                sxa += pxm; sya += pym;
                vm |= ((unsigned)mk) << (8 + e1 * 4 + 0);
            }
            {   // e2 = 1: X = -hw2
                float tt = (-hw2 - x1) * rdxe[e1];
                float py = fmaf(tt, dye[e1], y1);
                float uu = (hh2 - py) * (-r2h);
                bool mk = (tt > 0.0f) && (tt < 1.0f) && (uu > 0.0f) && (uu < 1.0f);
                pvar[e1 * 4 + 1] = py;
                float pxm = mk ? -hw2 : 0.0f, pym = mk ? py : 0.0f;
                LDSV(8 + e1 * 4 + 1) = packh2(pxm, pym);
                sxb += pxm; syb += pym;
                vm |= ((unsigned)mk) << (8 + e1 * 4 + 1);
            }
            {   // e2 = 2: Y = -hh2
                float tt = (-hh2 - y1) * rdye[e1];
                float px = fmaf(tt, dxe[e1], x1);
                float uu = (-hw2 - px) * r2w;
                bool mk = (tt > 0.0f) && (tt < 1.0f) && (uu > 0.0f) && (uu < 1.0f);
                pvar[e1 * 4 + 2] = px;
                float pxm = mk ? px : 0.0f, pym = mk ? -hh2 : 0.0f;
                LDSV(8 + e1 * 4 + 2) = packh2(pxm, pym);
                sxa += pxm; sya += pym;
                vm |= ((unsigned)mk) << (8 + e1 * 4 + 2);
            }
            {   // e2 = 3: X = +hw2
                float tt = (hw2 - x1) * rdxe[e1];
                float py = fmaf(tt, dye[e1], y1);
                float uu = (-hh2 - py) * r2h;
                bool mk = (tt > 0.0f) && (tt < 1.0f) && (uu > 0.0f) && (uu < 1.0f);
                pvar[e1 * 4 + 3] = py;
                float pxm = mk ? hw2 : 0.0f, pym = mk ? py : 0.0f;
                LDSV(8 + e1 * 4 + 3) = packh2(pxm, pym);
                sxb += pxm; syb += pym;
                vm |= ((unsigned)mk) << (8 + e1 * 4 + 3);
            }
        }
        float sx = sxa + sxb, sy = sya + syb;

        int nv = __popc(vm);
        float r0 = prcp(fmaxf((float)nv, 1.0f));
        float mx = sx * r0, my = sy * r0;

        unsigned ka[24];
#define MKKEY(K, XR, YR) do { \
        float xr_ = (XR), yr_ = (YR); \
        float d_ = fabsf(xr_) + fabsf(yr_); \
        float q_ = 1.0f - xr_ * prcp(d_); \
        float pa_ = copysignf(q_, yr_) + 4.0f; \
        unsigned key_ = (__float_as_uint(pa_) & 0xFFFFFFE0u) | (unsigned)(K); \
        ka[K] = ((vm >> (K)) & 1u) ? key_ : (0x7F000000u | (unsigned)(K)); \
    } while (0)
        float hpx = hw2 - mx, hmx = -hw2 - mx, hpy = hh2 - my, hmy = -hh2 - my;
#pragma unroll
        for (int k = 0; k < 4; k++) MKKEY(k, fx[k] - mx, fy[k] - my);
        MKKEY(4, hpx, hpy); MKKEY(5, hmx, hpy); MKKEY(6, hmx, hmy); MKKEY(7, hpx, hmy);
#pragma unroll
        for (int e1 = 0; e1 < 4; e1++) {
            MKKEY(8 + e1 * 4 + 0, pvar[e1 * 4 + 0] - mx, hpy);
            MKKEY(8 + e1 * 4 + 1, hmx, pvar[e1 * 4 + 1] - my);
            MKKEY(8 + e1 * 4 + 2, pvar[e1 * 4 + 2] - mx, hmy);
            MKKEY(8 + e1 * 4 + 3, hpx, pvar[e1 * 4 + 3] - my);
        }
#undef MKKEY

        // Batcher odd-even mergesort, n=24 (132 CEs), u32 min/max
#define CE(A, B) { unsigned lo_ = ka[A] < ka[B] ? ka[A] : ka[B]; \
                   unsigned hi_ = ka[A] < ka[B] ? ka[B] : ka[A]; \
                   ka[A] = lo_; ka[B] = hi_; }
        CE(0,1); CE(2,3); CE(4,5); CE(6,7); CE(8,9); CE(10,11); CE(12,13); CE(14,15); CE(16,17); CE(18,19); CE(20,21); CE(22,23);
        CE(0,2); CE(1,3); CE(4,6); CE(5,7); CE(8,10); CE(9,11); CE(12,14); CE(13,15); CE(16,18); CE(17,19); CE(20,22); CE(21,23);
        CE(1,2); CE(5,6); CE(9,10); CE(13,14); CE(17,18); CE(21,22);
        CE(0,4); CE(1,5); CE(2,6); CE(3,7); CE(8,12); CE(9,13); CE(10,14); CE(11,15); CE(16,20); CE(17,21); CE(18,22); CE(19,23);
        CE(2,4); CE(3,5); CE(10,12); CE(11,13); CE(18,20); CE(19,21);
        CE(1,2); CE(3,4); CE(5,6); CE(9,10); CE(11,12); CE(13,14); CE(17,18); CE(19,20); CE(21,22);
        CE(0,8); CE(1,9); CE(2,10); CE(3,11); CE(4,12); CE(5,13); CE(6,14); CE(7,15);
        CE(4,8); CE(5,9); CE(6,10); CE(7,11);
        CE(2,4); CE(3,5); CE(6,8); CE(7,9); CE(10,12); CE(11,13); CE(18,20); CE(19,21);
        CE(1,2); CE(3,4); CE(5,6); CE(7,8); CE(9,10); CE(11,12); CE(13,14); CE(17,18); CE(19,20); CE(21,22);
        CE(0,16); CE(1,17); CE(2,18); CE(3,19); CE(4,20); CE(5,21); CE(6,22); CE(7,23);
        CE(8,16); CE(9,17); CE(10,18); CE(11,19); CE(12,20); CE(13,21); CE(14,22); CE(15,23);
        CE(4,8); CE(5,9); CE(6,10); CE(7,11); CE(12,16); CE(13,17); CE(14,18); CE(15,19);
        CE(2,4); CE(3,5); CE(6,8); CE(7,9); CE(10,12); CE(11,13); CE(14,16); CE(15,17); CE(18,20); CE(19,21);
        CE(1,2); CE(3,4); CE(5,6); CE(7,8); CE(9,10); CE(11,12); CE(13,14); CE(15,16); CE(17,18); CE(19,20); CE(21,22);
#undef CE

        // gather sorted vertices; ref-exact cyclic shoelace with 4 rotating accumulators
        unsigned gu[24];
#pragma unroll
        for (int i = 0; i < 24; i++) gu[i] = ldsbuf[((ka[i] & 31u) << 7) + tid];
        float g0x, g0y;
        unpackh2(gu[0], g0x, g0y);
        float prevx = g0x, prevy = g0y;
        float ar0 = 0.0f, ar1 = 0.0f, ar2 = 0.0f, ar3 = 0.0f;
#pragma unroll
        for (int i = 1; i < 24; i++) {
            float xx, yy;
            unpackh2(gu[i], xx, yy);
            bool c = i < nv;
            float cxv = c ? xx : g0x;
            float cyv = c ? yy : g0y;
            float cr = prevx * cyv - cxv * prevy;
            if ((i & 3) == 0) ar0 += cr;
            else if ((i & 3) == 1) ar1 += cr;
            else if ((i & 3) == 2) ar2 += cr;
            else ar3 += cr;
            prevx = cxv; prevy = cyv;
        }
        ar0 += prevx * g0y - g0x * prevy;
        float area2 = (ar0 + ar1) + (ar2 + ar3);
        float inter2d = 0.5f * fabsf(area2);

        float inter3d = inter2d * zov;
        float uni = volsum - inter3d;
        float iou = inter3d / uni;
        loss = (1.0f - iou) * w;
    }
#undef LDSV

    // block reduction: wave shuffle + 2-wave LDS combine
#pragma unroll
    for (int off = 32; off > 0; off >>= 1) loss += __shfl_down(loss, off, 64);
    __shared__ float sm[THREADS / 64];
    int lane = threadIdx.x & 63, wv = threadIdx.x >> 6;
    if (lane == 0) sm[wv] = loss;
    __syncthreads();
    if (threadIdx.x == 0) {
        float s = 0.0f;
#pragma unroll
        for (int k = 0; k < THREADS / 64; k++) s += sm[k];
        partial[blockIdx.x] = s;
    }
}

__global__ void __launch_bounds__(1024) reduce_kernel(const float* __restrict__ partial,
                                                      int nb, float* __restrict__ out, int N) {
    float s = 0.0f;
    for (int i = threadIdx.x; i < nb; i += 1024) s += partial[i];
#pragma unroll
    for (int off = 32; off > 0; off >>= 1) s += __shfl_down(s, off, 64);
    __shared__ float sm[16];
    int lane = threadIdx.x & 63, wv = threadIdx.x >> 6;
    if (lane == 0) sm[wv] = s;
    __syncthreads();
    if (threadIdx.x == 0) {
        float tot = 0.0f;
#pragma unroll
        for (int k = 0; k < 16; k++) tot += sm[k];
        out[0] = tot / (float)N;
    }
}

extern "C" void kernel_launch(void* const* d_in, const int* in_sizes, int n_in,
                              void* d_out, int out_size, void* d_ws, size_t ws_size,
                              hipStream_t stream) {
    const float* pred = (const float*)d_in[0];
    const float* tgt  = (const float*)d_in[1];
    const float* wgt  = (const float*)d_in[2];
    int N = in_sizes[2];
    int nb = (N + THREADS - 1) / THREADS;
    float* partial = (float*)d_ws;
    iou3d_kernel<<<nb, THREADS, 0, stream>>>(pred, tgt, wgt, partial, N);
    reduce_kernel<<<1, 1024, 0, stream>>>(partial, nb, (float*)d_out, N);
}